// Round 9
// baseline (133.466 us; speedup 1.0000x reference)
//
#include <hip/hip_runtime.h>

// CostConcatenation: out[b,d,h,w, 0:16] = left[b,h,w,:]        (if valid else 0)
//                    out[b,d,h,w,16:32] = right[b,h,w-disp,:]  (if valid else 0)
// disp = d - 112 ; idx = w + (112 - d) ; valid = 0<=idx<W
// Output (B, D, H, W, 2C) fp32 = 604 MB -> write-BW bound.
// History: R1 plain 129us. R3 nt 118us. R4 d-tile null. R5 sc0/sc1 nan (L2
// poison lines flush over bypassing stores -> never bypass L2 on this harness).
// R6 XCD stripe -6%. R7 persistent linear sweep 115.9us (5.2 TB/s). R8
// branchless clamped loads -3% (extra invalid-region loads).
// R9: deepen the VMEM pipeline. Two-phase groups of 8: issue 8 independent
// guarded loads into registers, then 8 nt stores. Store vmcnt no longer chains
// directly behind a ~200cy L2 load; 8 load+store pairs in flight per wave.

constexpr int B_ = 2;
constexpr int H_ = 96;
constexpr int W_ = 192;
constexpr int D_ = 128;

typedef float v4f __attribute__((ext_vector_type(4)));

constexpr unsigned TOTAL4   = 37748736u;      // B*D*H*W*8 float4 (604 MB)
constexpr unsigned NBLK     = 2048u;          // 8 blocks/CU
constexpr unsigned NTHREADS = NBLK * 256u;    // 524288
constexpr int      ITERS    = TOTAL4 / NTHREADS;  // 72
constexpr int      GU       = 8;              // pipeline depth
constexpr int      NGROUP   = ITERS / GU;     // 9

__global__ __launch_bounds__(256) void cost_concat_kernel(
    const v4f* __restrict__ left,
    const v4f* __restrict__ right,
    v4f* __restrict__ out)
{
    unsigned j0 = blockIdx.x * 256u + threadIdx.x;

    for (int g = 0; g < NGROUP; ++g) {
        v4f v[GU];

        // Phase 1: issue GU independent guarded loads (compiler keeps all
        // in flight; waitcnt only before the dependent store).
        unsigned jj = j0;
        #pragma unroll
        for (int k = 0; k < GU; ++k, jj += NTHREADS) {
            const unsigned rowid = jj / 1536u;           // magic mul
            const unsigned rr    = jj - rowid * 1536u;
            const unsigned w     = rr >> 3;
            const unsigned c4    = rr & 7u;
            const unsigned b     = rowid / 12288u;       // 128*96
            const unsigned t     = rowid - b * 12288u;
            const unsigned d     = t / 96u;
            const unsigned h     = t - d * 96u;

            const int idx = (int)w + 112 - (int)d;       // right-image column
            const unsigned rowBase = (b * H_ + h) * (W_ * 4);

            v[k] = (v4f)(0.f);
            if ((unsigned)idx < (unsigned)W_) {
                const v4f* src = (c4 < 4u)
                    ? (left  + rowBase + w * 4u + c4)
                    : (right + rowBase + (unsigned)idx * 4u + (c4 - 4u));
                v[k] = *src;
            }
        }

        // Phase 2: drain as nt stores (each waits only on its own load).
        jj = j0;
        #pragma unroll
        for (int k = 0; k < GU; ++k, jj += NTHREADS) {
            __builtin_nontemporal_store(v[k], out + jj);
        }

        j0 += GU * NTHREADS;
    }
}

extern "C" void kernel_launch(void* const* d_in, const int* in_sizes, int n_in,
                              void* d_out, int out_size, void* d_ws, size_t ws_size,
                              hipStream_t stream)
{
    const v4f* left  = (const v4f*)d_in[0];
    const v4f* right = (const v4f*)d_in[1];
    v4f* out = (v4f*)d_out;

    cost_concat_kernel<<<dim3(NBLK), 256, 0, stream>>>(left, right, out);
}

// Round 10
// 130.678 us; speedup vs baseline: 1.0213x; 1.0213x over previous
//
#include <hip/hip_runtime.h>

// CostConcatenation: out[b,d,h,w, 0:16] = left[b,h,w,:]        (if valid else 0)
//                    out[b,d,h,w,16:32] = right[b,h,w-disp,:]  (if valid else 0)
// disp = d - 112 ; idx = w + (112 - d) ; valid = 0<=idx<W
// Output (B, D, H, W, 2C) fp32 = 604 MB -> write-BW bound.
// History: R1 plain 129us. R3 nt 118us. R4 d-tile null. R5 sc0/sc1 nan.
// R6 XCD stripe -6%. R7 persistent linear sweep 115.9us (5.2 TB/s; fill
// comparator 6.76 TB/s @ 10.9% occupancy). R8 branchless -3%. R9 8-deep
// pipeline -13%.
// R10: memcpy-shape. Fill hits 6.7 TB/s with ~3.5 waves/CU -> write BW needs
// no occupancy; what it has that we lack is ONE sequential stream per CU.
// R7's 8 blocks/CU emit 8 interleaved streams 8 MB apart, fragmenting the
// L2-writeback/DRAM-page stream. Here: 512 blocks (2/CU), each owning a
// CONTIGUOUS 1.18 MB segment, swept sequentially 4 KB/iteration.

constexpr int B_ = 2;
constexpr int H_ = 96;
constexpr int W_ = 192;
constexpr int D_ = 128;

typedef float v4f __attribute__((ext_vector_type(4)));

constexpr unsigned TOTAL4  = 37748736u;          // B*D*H*W*8 float4 (604 MB)
constexpr unsigned NBLK    = 512u;               // 2 blocks/CU
constexpr unsigned SEG     = TOTAL4 / NBLK;      // 73728 float4 = 1.125 MB per block
constexpr int      ITERS   = SEG / 256u;         // 288 sequential 4 KB chunks

__global__ __launch_bounds__(256) void cost_concat_kernel(
    const v4f* __restrict__ left,
    const v4f* __restrict__ right,
    v4f* __restrict__ out)
{
    unsigned j = blockIdx.x * SEG + threadIdx.x;

    #pragma unroll 4
    for (int it = 0; it < ITERS; ++it, j += 256u) {
        // decode flat float4 index -> (rowid, w, c4); rowid = (b*128+d)*96+h
        const unsigned rowid = j / 1536u;            // magic mul
        const unsigned rr    = j - rowid * 1536u;
        const unsigned w     = rr >> 3;
        const unsigned c4    = rr & 7u;
        const unsigned b     = rowid / 12288u;       // 128*96
        const unsigned t     = rowid - b * 12288u;
        const unsigned d     = t / 96u;              // magic mul
        const unsigned h     = t - d * 96u;

        const int idx = (int)w + 112 - (int)d;       // right-image column
        const unsigned rowBase = (b * H_ + h) * (W_ * 4);  // input row, float4

        v4f v = (v4f)(0.f);
        if ((unsigned)idx < (unsigned)W_) {
            const v4f* src = (c4 < 4u)
                ? (left  + rowBase + w * 4u + c4)
                : (right + rowBase + (unsigned)idx * 4u + (c4 - 4u));
            v = *src;
        }
        __builtin_nontemporal_store(v, out + j);
    }
}

extern "C" void kernel_launch(void* const* d_in, const int* in_sizes, int n_in,
                              void* d_out, int out_size, void* d_ws, size_t ws_size,
                              hipStream_t stream)
{
    const v4f* left  = (const v4f*)d_in[0];
    const v4f* right = (const v4f*)d_in[1];
    v4f* out = (v4f*)d_out;

    cost_concat_kernel<<<dim3(NBLK), 256, 0, stream>>>(left, right, out);
}

// Round 11
// 120.013 us; speedup vs baseline: 1.1121x; 1.0889x over previous
//
#include <hip/hip_runtime.h>

// CostConcatenation: out[b,d,h,w, 0:16] = left[b,h,w,:]        (if valid else 0)
//                    out[b,d,h,w,16:32] = right[b,h,w-disp,:]  (if valid else 0)
// disp = d - 112 ; idx = w + (112 - d) ; valid = 0<=idx<W
// Output (B, D, H, W, 2C) fp32 = 604 MB -> write-BW bound.
// History: R1 129us. R3 nt 118us. R4 d-tile null. R5 sc0/sc1 nan. R6 XCD -6%.
// R7 persistent linear 115.9us (5.2 TB/s; fill comparator 6.76 TB/s). R8
// branchless -3%. R9 deep pipeline -13%. R10 memcpy-shape -11%.
// R11: remove ALL global loads from the store loop. Stage the (b,h) row pair
// (24 KB) into LDS once per block; steady state = ds_read_b128 + nt store,
// structurally identical to the fill kernel. LDS demand ~8.5 B/cyc/CU = 3%
// of LDS BW -> bank conflicts irrelevant. Block covers DT=16 d-planes.

constexpr int B_ = 2;
constexpr int H_ = 96;
constexpr int W_ = 192;
constexpr int D_ = 128;
constexpr int DT = 16;                  // d-values per block
constexpr int ROW4 = W_ * 4;            // 768 float4 per input row

typedef float v4f __attribute__((ext_vector_type(4)));

__global__ __launch_bounds__(256) void cost_concat_kernel(
    const v4f* __restrict__ left,
    const v4f* __restrict__ right,
    v4f* __restrict__ out)
{
    __shared__ v4f lds[2 * ROW4];       // [0,768) = left row, [768,1536) = right row

    const int h  = blockIdx.x;
    const int d0 = blockIdx.y * DT;
    const int b  = blockIdx.z;
    const int tid = threadIdx.x;

    const int rowBase = (b * H_ + h) * ROW4;    // float4 units
    const v4f* __restrict__ lrow = left  + rowBase;
    const v4f* __restrict__ rrow = right + rowBase;

    // Stage both input rows into LDS (once per block, 6 coalesced passes).
    #pragma unroll
    for (int k = tid; k < 2 * ROW4; k += 256)
        lds[k] = (k < ROW4) ? lrow[k] : rrow[k - ROW4];
    __syncthreads();

    // Output: base for (b,d0,h); d-stride = H*W*8 float4
    long long outBase =
        (((long long)(b * D_ + d0)) * H_ + h) * (long long)(W_ * 8);
    const long long dStride = (long long)H_ * (W_ * 8);

    const int  c      = tid & 3;        // float4 slot within the half
    const bool isLeft = (tid & 7) < 4;

    for (int dd = 0; dd < DT; ++dd) {
        const int shift = 112 - (d0 + dd);      // idx = w + shift
        v4f* __restrict__ orow = out + outBase;

        #pragma unroll
        for (int k = 0; k < 6; ++k) {
            const int j   = tid + 256 * k;
            const int w   = j >> 3;
            const int idx = w + shift;

            v4f v = (v4f)(0.f);
            if ((unsigned)idx < (unsigned)W_) {
                // pure LDS read in steady state — no global loads in this loop
                v = isLeft ? lds[w * 4 + c] : lds[ROW4 + idx * 4 + c];
            }
            __builtin_nontemporal_store(v, orow + j);
        }
        outBase += dStride;
    }
}

extern "C" void kernel_launch(void* const* d_in, const int* in_sizes, int n_in,
                              void* d_out, int out_size, void* d_ws, size_t ws_size,
                              hipStream_t stream)
{
    const v4f* left  = (const v4f*)d_in[0];
    const v4f* right = (const v4f*)d_in[1];
    v4f* out = (v4f*)d_out;

    dim3 grid(H_, D_ / DT, B_);   // 96 * 8 * 2 = 1536 blocks, 384 KB written each
    cost_concat_kernel<<<grid, 256, 0, stream>>>(left, right, out);
}